// Round 1
// baseline (2594.954 us; speedup 1.0000x reference)
//
#include <hip/hip_runtime.h>
#include <math.h>

#define NN 50000
#define NE 1000000
#define NG 256
#define ORIGD 92
#define ATOMD 64
#define NBRD 41
#define KTOT 169
#define CO 128
#define TE 64
#define NSPREAD 32

// ---- workspace layout (float offsets). total ~26 MB ----
#define OFF_AF      0                        // 50000*64 = 3,200,000
#define OFF_SUMMED  3200000                  // 50000*64 = 3,200,000
#define OFF_WSW     6400000                  // 172*128 = 22016 (fc_W padded to K=172)
#define OFF_BN1SPR  (OFF_WSW + 22016)        // 32*256 spread accumulators (sum|sq)
#define OFF_BN1SC   (OFF_BN1SPR + 8192)      // 256: scale[128], shift[128]
#define OFF_BN2ACC  (OFF_BN1SC + 256)        // 128: sum[64], sq[64]
#define OFF_BN2SC   (OFF_BN2ACC + 128)       // 128: scale[64], shift[64]
#define OFF_ELOG    (OFF_BN2SC + 128)        // 50000: logits then exp()
#define OFF_SEGMAX  (OFF_ELOG + 50000)       // 256 (uint-encoded max)
#define OFF_DENOM   (OFF_SEGMAX + 256)       // 256
#define OFF_CRYS    (OFF_DENOM + 256)        // 256*64 = 16384
#define OFF_END     (OFF_CRYS + 16384)

// ---------------- embed: af = x@emb_W + emb_b + lower_f ----------------
__global__ __launch_bounds__(256) void k_embed(
    const float* __restrict__ x, const float* __restrict__ lf,
    const float* __restrict__ W, const float* __restrict__ b,
    float* __restrict__ af)
{
    int gid = blockIdx.x * 256 + threadIdx.x;      // 3.2M threads
    int n = gid >> 6, c = gid & 63;
    const float* xr = x + (long)n * ORIGD;
    float acc = b[c] + lf[gid];
#pragma unroll 4
    for (int k = 0; k < ORIGD; k++)
        acc = fmaf(xr[k], W[k * 64 + c], acc);
    af[gid] = acc;
}

// ---------------- pad fc_W from 169 to 172 rows (zeros) ----------------
__global__ void k_padw(const float* __restrict__ fcW, float* __restrict__ wsW)
{
    int i = blockIdx.x * 256 + threadIdx.x;        // 22016 threads
    wsW[i] = (i < KTOT * CO) ? fcW[i] : 0.f;
}

// ---------------- register-tiled MAC over one A-segment ----------------
template <int KLEN, int STRIDE>
__device__ __forceinline__ void mac_seg(const float* __restrict__ sbuf,
                                        const float* __restrict__ W,
                                        int eb, int ca, int cb, float* acc /*[4][8]*/)
{
    for (int k = 0; k < KLEN; k += 4) {
        float4 av[4];
#pragma unroll
        for (int e = 0; e < 4; e++)
            av[e] = *(const float4*)(sbuf + (eb + e) * STRIDE + k);
#pragma unroll
        for (int kk = 0; kk < 4; kk++) {
            const float* wr = W + (k + kk) * CO;
            float4 b0 = *(const float4*)(wr + ca);
            float4 b1 = *(const float4*)(wr + cb);
#pragma unroll
            for (int e = 0; e < 4; e++) {
                float aa = ((const float*)&av[e])[kk];
                acc[e*8+0] = fmaf(aa, b0.x, acc[e*8+0]);
                acc[e*8+1] = fmaf(aa, b0.y, acc[e*8+1]);
                acc[e*8+2] = fmaf(aa, b0.z, acc[e*8+2]);
                acc[e*8+3] = fmaf(aa, b0.w, acc[e*8+3]);
                acc[e*8+4] = fmaf(aa, b1.x, acc[e*8+4]);
                acc[e*8+5] = fmaf(aa, b1.y, acc[e*8+5]);
                acc[e*8+6] = fmaf(aa, b1.z, acc[e*8+6]);
                acc[e*8+7] = fmaf(aa, b1.w, acc[e*8+7]);
            }
        }
    }
}

// common staging of 64 edges' gathered rows into LDS
#define STAGE_EDGES()                                                        \
    int tid = threadIdx.x;                                                   \
    int e0 = blockIdx.x * TE;                                                \
    if (tid < TE) sS[tid] = ei[e0 + tid];                                    \
    else if (tid < 2 * TE) sT[tid - TE] = ei[NE + e0 + tid - TE];            \
    __syncthreads();                                                         \
    for (int i = tid; i < TE * 64; i += 256) {                               \
        int e = i >> 6, c = i & 63;                                          \
        sA[e * 68 + c] = af[(long)sS[e] * 64 + c];                           \
        sD[e * 68 + c] = af[(long)sT[e] * 64 + c];                           \
    }                                                                        \
    for (int i = tid; i < TE * 44; i += 256) {                               \
        int e = i / 44, c = i - e * 44;                                      \
        sE[e * 44 + c] = (c < NBRD) ? ea[(long)(e0 + e) * NBRD + c] : 0.f;   \
    }                                                                        \
    __syncthreads();

// ---------------- pass 1: GEMM + per-column sum / sum-of-squares ----------------
__global__ __launch_bounds__(256) void k_gemm_stats(
    const float* __restrict__ af, const float* __restrict__ ea,
    const int* __restrict__ ei, const float* __restrict__ W,
    float* __restrict__ spread)
{
    __shared__ float sA[TE * 68];
    __shared__ float sD[TE * 68];
    __shared__ float sE[TE * 44];
    __shared__ int   sS[TE], sT[TE];
    __shared__ float red[16 * 264];
    STAGE_EDGES();

    int cg = tid & 15, eg = tid >> 4;
    int eb = eg * 4, ca = cg * 8, cb = ca + 4;
    float acc[32];
#pragma unroll
    for (int i = 0; i < 32; i++) acc[i] = 0.f;

    mac_seg<64, 68>(sA, W,            eb, ca, cb, acc);
    mac_seg<64, 68>(sD, W + 64 * CO,  eb, ca, cb, acc);
    mac_seg<44, 44>(sE, W + 128 * CO, eb, ca, cb, acc);

    // per-thread reduce over 4 edges, write to LDS tree
#pragma unroll
    for (int c = 0; c < 8; c++) {
        float s = 0.f, q = 0.f;
#pragma unroll
        for (int e = 0; e < 4; e++) { float v = acc[e*8+c]; s += v; q = fmaf(v, v, q); }
        red[eg * 264 + ca + c]       = s;
        red[eg * 264 + 128 + ca + c] = q;
    }
    __syncthreads();
    float v = 0.f;
#pragma unroll 4
    for (int g = 0; g < 16; g++) v += red[g * 264 + tid];
    atomicAdd(&spread[(blockIdx.x & (NSPREAD - 1)) * 256 + tid], v);
}

// ---------------- bn1 finalize: scale/shift (bias folded) ----------------
__global__ void k_bn1fin(const float* __restrict__ spread,
                         const float* __restrict__ g, const float* __restrict__ b,
                         float* __restrict__ sc)
{
    int c = threadIdx.x;  // 128
    float s = 0.f, q = 0.f;
    for (int k = 0; k < NSPREAD; k++) { s += spread[k * 256 + c]; q += spread[k * 256 + 128 + c]; }
    float mean_acc = s / (float)NE;                    // mean of (total@W), bias excluded
    float var = q / (float)NE - mean_acc * mean_acc;   // bias shift doesn't change var
    float scale = g[c] * rsqrtf(var + 1e-5f);
    sc[c] = scale;
    sc[128 + c] = b[c] - mean_acc * scale;             // normalized = acc*scale + shift
}

// ---------------- pass 2: GEMM + BN + gate + scatter-add ----------------
__global__ __launch_bounds__(256) void k_gemm_msg(
    const float* __restrict__ af, const float* __restrict__ ea,
    const int* __restrict__ ei, const float* __restrict__ W,
    const float* __restrict__ sc, float* __restrict__ summed)
{
    __shared__ float sA[TE * 68];
    __shared__ float sD[TE * 68];
    __shared__ float sE[TE * 44];
    __shared__ int   sS[TE], sT[TE];
    STAGE_EDGES();

    int cg = tid & 15, eg = tid >> 4;
    int eb = eg * 4, ca = cg * 4, cb = ca + 64;   // filter col + matching core col
    float acc[32];
#pragma unroll
    for (int i = 0; i < 32; i++) acc[i] = 0.f;

    mac_seg<64, 68>(sA, W,            eb, ca, cb, acc);
    mac_seg<64, 68>(sD, W + 64 * CO,  eb, ca, cb, acc);
    mac_seg<44, 44>(sE, W + 128 * CO, eb, ca, cb, acc);

    float scA[4], shA[4], scB[4], shB[4];
#pragma unroll
    for (int j = 0; j < 4; j++) {
        scA[j] = sc[ca + j];  shA[j] = sc[128 + ca + j];
        scB[j] = sc[cb + j];  shB[j] = sc[128 + cb + j];
    }
#pragma unroll
    for (int e = 0; e < 4; e++) {
        int src = sS[eb + e];
#pragma unroll
        for (int j = 0; j < 4; j++) {
            float f  = fmaf(acc[e*8+j],     scA[j], shA[j]);
            float cc = fmaf(acc[e*8+4+j],   scB[j], shB[j]);
            float sig = 1.f / (1.f + expf(-f));
            float sp  = fmaxf(cc, 0.f) + log1pf(expf(-fabsf(cc)));  // stable softplus
            atomicAdd(&summed[(long)src * 64 + ca + j], sig * sp);
        }
    }
}

// ---------------- bn2 stats over summed (50000 x 64) ----------------
__global__ __launch_bounds__(256) void k_bn2stats(const float* __restrict__ summed,
                                                  float* __restrict__ acc2)
{
    int tid = threadIdx.x; int c = tid & 63; int sub = tid >> 6;
    float s = 0.f, q = 0.f;
    for (int r = blockIdx.x * 4 + sub; r < NN; r += 4 * 128) {
        float v = summed[(long)r * 64 + c]; s += v; q = fmaf(v, v, q);
    }
    __shared__ float rs[256], rq[256];
    rs[tid] = s; rq[tid] = q; __syncthreads();
    if (tid < 64) {
        s = rs[tid] + rs[tid + 64] + rs[tid + 128] + rs[tid + 192];
        q = rq[tid] + rq[tid + 64] + rq[tid + 128] + rq[tid + 192];
        atomicAdd(&acc2[tid], s);
        atomicAdd(&acc2[64 + tid], q);
    }
}

__global__ void k_bn2fin(const float* __restrict__ acc2,
                         const float* __restrict__ g, const float* __restrict__ b,
                         float* __restrict__ sc2)
{
    int c = threadIdx.x;  // 64
    float mean = acc2[c] / (float)NN;
    float var = acc2[64 + c] / (float)NN - mean * mean;
    float scale = g[c] * rsqrtf(var + 1e-5f);
    sc2[c] = scale;
    sc2[64 + c] = b[c] - mean * scale;
}

// ---------------- atom_out write + silu + logits + segment max ----------------
__global__ __launch_bounds__(256) void k_nodepost(
    const float* __restrict__ summed, const float* __restrict__ sc2,
    const float* __restrict__ attW, const float* __restrict__ attb,
    const int* __restrict__ batch, float* __restrict__ out,
    float* __restrict__ elog, unsigned* __restrict__ segmax)
{
    int tid = threadIdx.x; int n = blockIdx.x * 4 + (tid >> 6); int c = tid & 63;
    float v = summed[(long)n * 64 + c];
    float ao = fmaf(v, sc2[c], sc2[64 + c]);
    out[(long)n * 64 + c] = ao;                       // output 0: atom_out
    float h = ao / (1.f + expf(-ao));                 // silu
    float p = h * attW[c];
#pragma unroll
    for (int off = 32; off; off >>= 1) p += __shfl_down(p, off, 64);
    if (c == 0) {
        float logit = p + attb[0];
        elog[n] = logit;
        unsigned u = __float_as_uint(logit);
        u = (u & 0x80000000u) ? ~u : (u | 0x80000000u);   // order-preserving encode
        atomicMax(&segmax[batch[n]], u);
    }
}

// ---------------- softmax denominator ----------------
__global__ void k_denom(const int* __restrict__ batch,
                        const unsigned* __restrict__ segmax,
                        float* __restrict__ elog, float* __restrict__ denom)
{
    int n = blockIdx.x * 256 + threadIdx.x;
    if (n >= NN) return;
    int b = batch[n];
    unsigned u = segmax[b];
    u = (u & 0x80000000u) ? (u & 0x7FFFFFFFu) : ~u;       // decode
    float e = expf(elog[n] - __uint_as_float(u));
    elog[n] = e;                                          // store exp for alpha
    atomicAdd(&denom[b], e);
}

// ---------------- weighted pooling ----------------
__global__ __launch_bounds__(256) void k_crys(
    const float* __restrict__ out, const float* __restrict__ elog,
    const float* __restrict__ denom, const int* __restrict__ batch,
    float* __restrict__ crys)
{
    int tid = threadIdx.x; int n = blockIdx.x * 4 + (tid >> 6); int c = tid & 63;
    int b = batch[n];
    float alpha = elog[n] / denom[b];
    float ao = out[(long)n * 64 + c];
    float h = ao / (1.f + expf(-ao));
    atomicAdd(&crys[b * 64 + c], alpha * h);
}

// ---------------- final projection ----------------
__global__ void k_final(const float* __restrict__ crys,
                        const float* __restrict__ outW, const float* __restrict__ outb,
                        float* __restrict__ out)
{
    int g = blockIdx.x; int c = threadIdx.x;  // 256 blocks x 64
    float p = crys[g * 64 + c] * outW[c];
#pragma unroll
    for (int off = 32; off; off >>= 1) p += __shfl_down(p, off, 64);
    if (c == 0) out[(long)NN * 64 + g] = p + outb[0];
}

extern "C" void kernel_launch(void* const* d_in, const int* in_sizes, int n_in,
                              void* d_out, int out_size, void* d_ws, size_t ws_size,
                              hipStream_t stream)
{
    const float* x    = (const float*)d_in[0];
    const float* eatt = (const float*)d_in[1];
    const float* lf   = (const float*)d_in[2];
    const int*   ei   = (const int*)d_in[3];
    const int*   batch= (const int*)d_in[4];
    const float* embW = (const float*)d_in[5];
    const float* embB = (const float*)d_in[6];
    const float* fcW  = (const float*)d_in[7];
    // d_in[8] fc_b folds into bn1 shift (linear before BN); not needed directly
    const float* bn1g = (const float*)d_in[9];
    const float* bn1b = (const float*)d_in[10];
    const float* bn2g = (const float*)d_in[11];
    const float* bn2b = (const float*)d_in[12];
    const float* attW = (const float*)d_in[13];
    const float* attB = (const float*)d_in[14];
    const float* outW = (const float*)d_in[15];
    const float* outB = (const float*)d_in[16];
    float* out = (float*)d_out;
    float* ws  = (float*)d_ws;

    // zero accumulator region (summed, spreads, segmax, denom, crys, ...)
    hipMemsetAsync(ws + OFF_SUMMED, 0, (size_t)(OFF_END - OFF_SUMMED) * sizeof(float), stream);

    k_embed<<<12500, 256, 0, stream>>>(x, lf, embW, embB, ws + OFF_AF);
    k_padw<<<86, 256, 0, stream>>>(fcW, ws + OFF_WSW);
    k_gemm_stats<<<NE / TE, 256, 0, stream>>>(ws + OFF_AF, eatt, ei, ws + OFF_WSW, ws + OFF_BN1SPR);
    k_bn1fin<<<1, 128, 0, stream>>>(ws + OFF_BN1SPR, bn1g, bn1b, ws + OFF_BN1SC);
    k_gemm_msg<<<NE / TE, 256, 0, stream>>>(ws + OFF_AF, eatt, ei, ws + OFF_WSW, ws + OFF_BN1SC, ws + OFF_SUMMED);
    k_bn2stats<<<128, 256, 0, stream>>>(ws + OFF_SUMMED, ws + OFF_BN2ACC);
    k_bn2fin<<<1, 64, 0, stream>>>(ws + OFF_BN2ACC, bn2g, bn2b, ws + OFF_BN2SC);
    k_nodepost<<<12500, 256, 0, stream>>>(ws + OFF_SUMMED, ws + OFF_BN2SC, attW, attB, batch,
                                          out, ws + OFF_ELOG, (unsigned*)(ws + OFF_SEGMAX));
    k_denom<<<196, 256, 0, stream>>>(batch, (const unsigned*)(ws + OFF_SEGMAX), ws + OFF_ELOG, ws + OFF_DENOM);
    k_crys<<<12500, 256, 0, stream>>>(out, ws + OFF_ELOG, ws + OFF_DENOM, batch, ws + OFF_CRYS);
    k_final<<<NG, 64, 0, stream>>>(ws + OFF_CRYS, outW, outB, out);
}

// Round 2
// 1679.086 us; speedup vs baseline: 1.5455x; 1.5455x over previous
//
#include <hip/hip_runtime.h>
#include <math.h>

#define NN 50000
#define NE 1000000
#define NG 256
#define ORIGD 92
#define NBRD 41
#define NSPREAD 32

typedef unsigned short u16;
typedef __attribute__((ext_vector_type(8))) short short8;   // 8 x bf16 MFMA frag
typedef __attribute__((ext_vector_type(4))) float f32x4;    // MFMA accumulator

// ---- workspace layout (float offsets) ----
#define OFF_AFB     0                        // 50000*64 bf16 = 1,600,000 floats
#define OFF_SUMMED  1600000                  // 50000*64 fp32
#define OFF_WT      4800000                  // 128*192 bf16 = 12288 floats
#define OFF_BN1SPR  4812288                  // 32*256
#define OFF_BN1SC   4820480                  // 256
#define OFF_BN2ACC  4820736                  // 128
#define OFF_BN2SC   4820864                  // 128
#define OFF_ELOG    4820992                  // 50000
#define OFF_SEGMAX  4870992                  // 256
#define OFF_DENOM   4871248                  // 256
#define OFF_CRYS    4871504                  // 256*64
#define OFF_END     4887888

__device__ __forceinline__ u16 f2b(float f) {          // fp32 -> bf16 RNE
    unsigned u = __float_as_uint(f);
    return (u16)((u + 0x7FFFu + ((u >> 16) & 1u)) >> 16);
}

// ---------------- embed: afb = bf16(x@emb_W + emb_b + lower_f) ----------------
__global__ __launch_bounds__(256) void k_embed(
    const float* __restrict__ x, const float* __restrict__ lf,
    const float* __restrict__ W, const float* __restrict__ b,
    u16* __restrict__ afb)
{
    int gid = blockIdx.x * 256 + threadIdx.x;      // 3.2M threads
    int n = gid >> 6, c = gid & 63;
    const float* xr = x + (long)n * ORIGD;
    float acc = b[c] + lf[gid];
#pragma unroll 4
    for (int k = 0; k < ORIGD; k++)
        acc = fmaf(xr[k], W[k * 64 + c], acc);
    afb[gid] = f2b(acc);
}

// ---------------- prep: wT[j][k] = bf16(fc_W[k][j]), K padded 169->192 ----------------
__global__ void k_prepw(const float* __restrict__ fcW, u16* __restrict__ wT)
{
    int i = blockIdx.x * 256 + threadIdx.x;        // 128*192 = 24576
    int j = i / 192, k = i - j * 192;
    wT[i] = (k < 169) ? f2b(fcW[k * 128 + j]) : (u16)0;
}

// ---------------- MFMA edge GEMM, MODE 0 = stats, MODE 1 = msg+scatter ----------------
// Per block: 64 edges x 128 cols. Wave w owns m-tiles {w, w+4} so filter col j and
// core col j+64 pair in the same lane/reg. B (edge rows) staged in LDS stride 200
// (16B-aligned rows; bank stride 100 dw = 4 mod 8 -> worst 2-way aliasing).
template <int MODE>
__global__ __launch_bounds__(256) void k_gemm(
    const u16* __restrict__ afb, const float* __restrict__ ea,
    const int* __restrict__ ei, const u16* __restrict__ wT,
    const float* __restrict__ sc, float* __restrict__ outbuf)
{
    __shared__ __align__(16) u16 sTl[64 * 200];
    __shared__ int sSrc[64], sDst[64];
    const int tid = threadIdx.x;
    const int e0 = blockIdx.x * 64;

    if (tid < 64) sSrc[tid] = ei[e0 + tid];
    else if (tid < 128) sDst[tid - 64] = ei[NE + e0 + tid - 64];
    __syncthreads();

    // stage af[src] (k 0..63) and af[dst] (k 64..127): 16-byte chunks
    for (int i = tid; i < 1024; i += 256) {
        int e = i >> 4, q = i & 15;
        const u16* g = (q < 8) ? (afb + (long)sSrc[e] * 64 + q * 8)
                               : (afb + (long)sDst[e] * 64 + (q - 8) * 8);
        *(short8*)(sTl + e * 200 + q * 8) = *(const short8*)g;
    }
    // stage edge_attr -> bf16 (k 128..191, zero-padded past col 41)
    for (int i = tid; i < 64 * 64; i += 256) {
        int e = i >> 6, c = i & 63;
        float v = (c < NBRD) ? ea[(long)(e0 + e) * NBRD + c] : 0.f;
        sTl[e * 200 + 128 + c] = f2b(v);
    }
    __syncthreads();

    const int lane = tid & 63, w = tid >> 6;
    const int n16 = lane & 15, quad = lane >> 4;

    // A-frags (W^T) straight from global (L2-resident 49 KB), hoisted: 12 frags
    short8 A0[6], A1[6];
    {
        const u16* b0 = wT + (16 * w + n16) * 192 + quad * 8;
        const u16* b1 = wT + (16 * (w + 4) + n16) * 192 + quad * 8;
#pragma unroll
        for (int ks = 0; ks < 6; ks++) {
            A0[ks] = *(const short8*)(b0 + ks * 32);
            A1[ks] = *(const short8*)(b1 + ks * 32);
        }
    }

    const int j0 = 16 * w + 4 * quad;   // filter col base for this lane's acc rows
    float s0[4] = {0,0,0,0}, q0[4] = {0,0,0,0}, s1[4] = {0,0,0,0}, q1[4] = {0,0,0,0};
    float scf[4], shf[4], scc[4], shc[4];
    if (MODE == 1) {
#pragma unroll
        for (int r = 0; r < 4; r++) {
            scf[r] = sc[j0 + r];        shf[r] = sc[128 + j0 + r];
            scc[r] = sc[64 + j0 + r];   shc[r] = sc[192 + j0 + r];
        }
    }

    for (int t = 0; t < 4; t++) {
        const u16* row = sTl + (16 * t + n16) * 200 + quad * 8;
        f32x4 acc0 = {0.f, 0.f, 0.f, 0.f}, acc1 = {0.f, 0.f, 0.f, 0.f};
#pragma unroll
        for (int ks = 0; ks < 6; ks++) {
            short8 b = *(const short8*)(row + ks * 32);
            acc0 = __builtin_amdgcn_mfma_f32_16x16x32_bf16(A0[ks], b, acc0, 0, 0, 0);
            acc1 = __builtin_amdgcn_mfma_f32_16x16x32_bf16(A1[ks], b, acc1, 0, 0, 0);
        }
        if (MODE == 0) {
#pragma unroll
            for (int r = 0; r < 4; r++) {
                s0[r] += acc0[r]; q0[r] = fmaf(acc0[r], acc0[r], q0[r]);
                s1[r] += acc1[r]; q1[r] = fmaf(acc1[r], acc1[r], q1[r]);
            }
        } else {
            int src = sSrc[16 * t + n16];
            float* dst = outbuf + (long)src * 64 + j0;
#pragma unroll
            for (int r = 0; r < 4; r++) {
                float f  = fmaf(acc0[r], scf[r], shf[r]);
                float cc = fmaf(acc1[r], scc[r], shc[r]);
                float sig = 1.f / (1.f + expf(-f));
                float sp  = fmaxf(cc, 0.f) + log1pf(expf(-fabsf(cc)));
                atomicAdd(dst + r, sig * sp);
            }
        }
    }

    if (MODE == 0) {
        // reduce over the 16 edge-lanes (quad fixed), then one lane writes
#pragma unroll
        for (int m = 1; m < 16; m <<= 1) {
#pragma unroll
            for (int r = 0; r < 4; r++) {
                s0[r] += __shfl_xor(s0[r], m); q0[r] += __shfl_xor(q0[r], m);
                s1[r] += __shfl_xor(s1[r], m); q1[r] += __shfl_xor(q1[r], m);
            }
        }
        if (n16 == 0) {
            float* sp = outbuf + (blockIdx.x & (NSPREAD - 1)) * 256;
#pragma unroll
            for (int r = 0; r < 4; r++) {
                atomicAdd(sp + j0 + r,            s0[r]);
                atomicAdd(sp + 128 + j0 + r,      q0[r]);
                atomicAdd(sp + 64 + j0 + r,       s1[r]);
                atomicAdd(sp + 192 + j0 + r,      q1[r]);
            }
        }
    }
}

// ---------------- bn1 finalize: scale/shift (fc_b folds out) ----------------
__global__ void k_bn1fin(const float* __restrict__ spread,
                         const float* __restrict__ g, const float* __restrict__ b,
                         float* __restrict__ sc)
{
    int c = threadIdx.x;  // 128
    float s = 0.f, q = 0.f;
    for (int k = 0; k < NSPREAD; k++) { s += spread[k * 256 + c]; q += spread[k * 256 + 128 + c]; }
    float mean_acc = s / (float)NE;
    float var = q / (float)NE - mean_acc * mean_acc;
    float scale = g[c] * rsqrtf(var + 1e-5f);
    sc[c] = scale;
    sc[128 + c] = b[c] - mean_acc * scale;
}

// ---------------- bn2 stats over summed (50000 x 64) ----------------
__global__ __launch_bounds__(256) void k_bn2stats(const float* __restrict__ summed,
                                                  float* __restrict__ acc2)
{
    int tid = threadIdx.x; int c = tid & 63; int sub = tid >> 6;
    float s = 0.f, q = 0.f;
    for (int r = blockIdx.x * 4 + sub; r < NN; r += 4 * 128) {
        float v = summed[(long)r * 64 + c]; s += v; q = fmaf(v, v, q);
    }
    __shared__ float rs[256], rq[256];
    rs[tid] = s; rq[tid] = q; __syncthreads();
    if (tid < 64) {
        s = rs[tid] + rs[tid + 64] + rs[tid + 128] + rs[tid + 192];
        q = rq[tid] + rq[tid + 64] + rq[tid + 128] + rq[tid + 192];
        atomicAdd(&acc2[tid], s);
        atomicAdd(&acc2[64 + tid], q);
    }
}

__global__ void k_bn2fin(const float* __restrict__ acc2,
                         const float* __restrict__ g, const float* __restrict__ b,
                         float* __restrict__ sc2)
{
    int c = threadIdx.x;  // 64
    float mean = acc2[c] / (float)NN;
    float var = acc2[64 + c] / (float)NN - mean * mean;
    float scale = g[c] * rsqrtf(var + 1e-5f);
    sc2[c] = scale;
    sc2[64 + c] = b[c] - mean * scale;
}

// ---------------- atom_out + silu + logits + segment max ----------------
__global__ __launch_bounds__(256) void k_nodepost(
    const float* __restrict__ summed, const float* __restrict__ sc2,
    const float* __restrict__ attW, const float* __restrict__ attb,
    const int* __restrict__ batch, float* __restrict__ out,
    float* __restrict__ elog, unsigned* __restrict__ segmax)
{
    int tid = threadIdx.x; int n = blockIdx.x * 4 + (tid >> 6); int c = tid & 63;
    float v = summed[(long)n * 64 + c];
    float ao = fmaf(v, sc2[c], sc2[64 + c]);
    out[(long)n * 64 + c] = ao;
    float h = ao / (1.f + expf(-ao));
    float p = h * attW[c];
#pragma unroll
    for (int off = 32; off; off >>= 1) p += __shfl_down(p, off, 64);
    if (c == 0) {
        float logit = p + attb[0];
        elog[n] = logit;
        unsigned u = __float_as_uint(logit);
        u = (u & 0x80000000u) ? ~u : (u | 0x80000000u);
        atomicMax(&segmax[batch[n]], u);
    }
}

__global__ void k_denom(const int* __restrict__ batch,
                        const unsigned* __restrict__ segmax,
                        float* __restrict__ elog, float* __restrict__ denom)
{
    int n = blockIdx.x * 256 + threadIdx.x;
    if (n >= NN) return;
    int b = batch[n];
    unsigned u = segmax[b];
    u = (u & 0x80000000u) ? (u & 0x7FFFFFFFu) : ~u;
    float e = expf(elog[n] - __uint_as_float(u));
    elog[n] = e;
    atomicAdd(&denom[b], e);
}

__global__ __launch_bounds__(256) void k_crys(
    const float* __restrict__ out, const float* __restrict__ elog,
    const float* __restrict__ denom, const int* __restrict__ batch,
    float* __restrict__ crys)
{
    int tid = threadIdx.x; int n = blockIdx.x * 4 + (tid >> 6); int c = tid & 63;
    int b = batch[n];
    float alpha = elog[n] / denom[b];
    float ao = out[(long)n * 64 + c];
    float h = ao / (1.f + expf(-ao));
    atomicAdd(&crys[b * 64 + c], alpha * h);
}

__global__ void k_final(const float* __restrict__ crys,
                        const float* __restrict__ outW, const float* __restrict__ outb,
                        float* __restrict__ out)
{
    int g = blockIdx.x; int c = threadIdx.x;
    float p = crys[g * 64 + c] * outW[c];
#pragma unroll
    for (int off = 32; off; off >>= 1) p += __shfl_down(p, off, 64);
    if (c == 0) out[(long)NN * 64 + g] = p + outb[0];
}

extern "C" void kernel_launch(void* const* d_in, const int* in_sizes, int n_in,
                              void* d_out, int out_size, void* d_ws, size_t ws_size,
                              hipStream_t stream)
{
    const float* x    = (const float*)d_in[0];
    const float* eatt = (const float*)d_in[1];
    const float* lf   = (const float*)d_in[2];
    const int*   ei   = (const int*)d_in[3];
    const int*   batch= (const int*)d_in[4];
    const float* embW = (const float*)d_in[5];
    const float* embB = (const float*)d_in[6];
    const float* fcW  = (const float*)d_in[7];
    // d_in[8] fc_b folds into bn1 shift
    const float* bn1g = (const float*)d_in[9];
    const float* bn1b = (const float*)d_in[10];
    const float* bn2g = (const float*)d_in[11];
    const float* bn2b = (const float*)d_in[12];
    const float* attW = (const float*)d_in[13];
    const float* attB = (const float*)d_in[14];
    const float* outW = (const float*)d_in[15];
    const float* outB = (const float*)d_in[16];
    float* out = (float*)d_out;
    float* ws  = (float*)d_ws;

    u16* afb = (u16*)(ws + OFF_AFB);
    u16* wT  = (u16*)(ws + OFF_WT);

    hipMemsetAsync(ws + OFF_SUMMED, 0, (size_t)(OFF_END - OFF_SUMMED) * sizeof(float), stream);

    k_embed<<<12500, 256, 0, stream>>>(x, lf, embW, embB, afb);
    k_prepw<<<96, 256, 0, stream>>>(fcW, wT);
    k_gemm<0><<<NE / 64, 256, 0, stream>>>(afb, eatt, ei, wT, ws + OFF_BN1SC, ws + OFF_BN1SPR);
    k_bn1fin<<<1, 128, 0, stream>>>(ws + OFF_BN1SPR, bn1g, bn1b, ws + OFF_BN1SC);
    k_gemm<1><<<NE / 64, 256, 0, stream>>>(afb, eatt, ei, wT, ws + OFF_BN1SC, ws + OFF_SUMMED);
    k_bn2stats<<<128, 256, 0, stream>>>(ws + OFF_SUMMED, ws + OFF_BN2ACC);
    k_bn2fin<<<1, 64, 0, stream>>>(ws + OFF_BN2ACC, bn2g, bn2b, ws + OFF_BN2SC);
    k_nodepost<<<12500, 256, 0, stream>>>(ws + OFF_SUMMED, ws + OFF_BN2SC, attW, attB, batch,
                                          out, ws + OFF_ELOG, (unsigned*)(ws + OFF_SEGMAX));
    k_denom<<<196, 256, 0, stream>>>(batch, (const unsigned*)(ws + OFF_SEGMAX), ws + OFF_ELOG, ws + OFF_DENOM);
    k_crys<<<12500, 256, 0, stream>>>(out, ws + OFF_ELOG, ws + OFF_DENOM, batch, ws + OFF_CRYS);
    k_final<<<NG, 64, 0, stream>>>(ws + OFF_CRYS, outW, outB, out);
}

// Round 3
// 1272.274 us; speedup vs baseline: 2.0396x; 1.3198x over previous
//
#include <hip/hip_runtime.h>
#include <math.h>

#define NN 50000
#define NE 1000000
#define NG 256
#define ORIGD 92
#define NBRD 41
#define NSPREAD 32
#define SCAN_B 256

typedef unsigned short u16;
typedef __attribute__((ext_vector_type(8))) short short8;   // 8 x bf16 MFMA frag
typedef __attribute__((ext_vector_type(4))) float f32x4;    // MFMA accumulator

// ---- workspace layout (float offsets) ----
#define OFF_AFB     0                        // 50000*64 bf16
#define OFF_SUMMED  1600000                  // 50000*64 fp32
#define OFF_WT      4800000                  // 128*192 bf16
#define OFF_BN1SPR  4812288                  // 32*256
#define OFF_BN1SC   4820480                  // 256
#define OFF_BN2ACC  4820736                  // 128
#define OFF_BN2SC   4820864                  // 128
#define OFF_ELOG    4820992                  // 50000
#define OFF_SEGMAX  4870992                  // 256
#define OFF_DENOM   4871248                  // 256
#define OFF_CRYS    4871504                  // 256*64
#define OFF_CNT     4887888                  // 50000 int
#define OFF_PTR     4937888                  // 50000 int (also lofs scratch)
#define OFF_HEAD    4987888                  // 50000 int
#define OFF_BSUM    5037888                  // 256 int
#define OFF_BOFS    5038144                  // 256 int
#define OFF_EIDX    5038400                  // 1M int
#define OFF_H       6038400                  // 1M*128 bf16 = 64M floats (256 MB)
#define OFF_BIG_END 70038400                 // floats; ~280 MB total

__device__ __forceinline__ u16 f2b(float f) {          // fp32 -> bf16 RNE
    unsigned u = __float_as_uint(f);
    return (u16)((u + 0x7FFFu + ((u >> 16) & 1u)) >> 16);
}
__device__ __forceinline__ float b2f(u16 u) {
    return __uint_as_float(((unsigned)u) << 16);
}

// ---------------- embed: afb = bf16(x@emb_W + emb_b + lower_f) ----------------
__global__ __launch_bounds__(256) void k_embed(
    const float* __restrict__ x, const float* __restrict__ lf,
    const float* __restrict__ W, const float* __restrict__ b,
    u16* __restrict__ afb)
{
    int gid = blockIdx.x * 256 + threadIdx.x;
    int n = gid >> 6, c = gid & 63;
    const float* xr = x + (long)n * ORIGD;
    float acc = b[c] + lf[gid];
#pragma unroll 4
    for (int k = 0; k < ORIGD; k++)
        acc = fmaf(xr[k], W[k * 64 + c], acc);
    afb[gid] = f2b(acc);
}

// ---------------- prep: wT[j][k] = bf16(fc_W[k][j]), K padded 169->192 ----------------
__global__ void k_prepw(const float* __restrict__ fcW, u16* __restrict__ wT)
{
    int i = blockIdx.x * 256 + threadIdx.x;        // 24576
    int j = i / 192, k = i - j * 192;
    wT[i] = (k < 169) ? f2b(fcW[k * 128 + j]) : (u16)0;
}

// ---------------- CSR build ----------------
__global__ void k_hist(const int* __restrict__ ei, int* __restrict__ cnt)
{
    int e = blockIdx.x * 256 + threadIdx.x;
    if (e < NE) atomicAdd(&cnt[ei[e]], 1);
}

__global__ void k_partial(const int* __restrict__ cnt, int* __restrict__ lofs,
                          int* __restrict__ bsum)
{
    __shared__ int sd[SCAN_B];
    int t = threadIdx.x, b = blockIdx.x, n = b * SCAN_B + t;
    int v = (n < NN) ? cnt[n] : 0;
    sd[t] = v; __syncthreads();
    for (int o = 1; o < SCAN_B; o <<= 1) {
        int x = (t >= o) ? sd[t - o] : 0;
        __syncthreads();
        sd[t] += x;
        __syncthreads();
    }
    if (n < NN) lofs[n] = sd[t] - v;               // exclusive within block
    if (t == SCAN_B - 1) bsum[b] = sd[t];
}

__global__ void k_scanb(const int* __restrict__ bsum, int* __restrict__ bofs, int nb)
{
    __shared__ int sd[256];
    int t = threadIdx.x;
    int v = (t < nb) ? bsum[t] : 0;
    sd[t] = v; __syncthreads();
    for (int o = 1; o < 256; o <<= 1) {
        int x = (t >= o) ? sd[t - o] : 0;
        __syncthreads();
        sd[t] += x;
        __syncthreads();
    }
    bofs[t] = sd[t] - v;
}

__global__ void k_addofs(int* __restrict__ ptr, const int* __restrict__ bofs,
                         int* __restrict__ head)
{
    int n = blockIdx.x * 256 + threadIdx.x;
    if (n < NN) {
        int p = ptr[n] + bofs[n >> 8];
        ptr[n] = p; head[n] = p;
    }
}

__global__ void k_fill(const int* __restrict__ ei, int* __restrict__ head,
                       int* __restrict__ eidx)
{
    int e = blockIdx.x * 256 + threadIdx.x;
    if (e < NE) {
        int pos = atomicAdd(&head[ei[e]], 1);
        eidx[pos] = e;
    }
}

// ---------------- single MFMA GEMM pass: h (bf16) + column stats ----------------
// 64 edges x 128 cols per block; wave w owns m-tiles {w, w+4}.
// LDS rows stride 200 u16 (bank stride 100 dw == 4 mod 8 -> worst 2-way aliasing).
__global__ __launch_bounds__(256) void k_gemm_h(
    const u16* __restrict__ afb, const float* __restrict__ ea,
    const int* __restrict__ ei, const u16* __restrict__ wT,
    u16* __restrict__ h, float* __restrict__ spread)
{
    __shared__ __align__(16) u16 sTl[64 * 200];
    __shared__ int sSrc[64], sDst[64];
    const int tid = threadIdx.x;
    const int e0 = blockIdx.x * 64;

    if (tid < 64) sSrc[tid] = ei[e0 + tid];
    else if (tid < 128) sDst[tid - 64] = ei[NE + e0 + tid - 64];
    __syncthreads();

    for (int i = tid; i < 1024; i += 256) {
        int e = i >> 4, q = i & 15;
        const u16* g = (q < 8) ? (afb + (long)sSrc[e] * 64 + q * 8)
                               : (afb + (long)sDst[e] * 64 + (q - 8) * 8);
        *(short8*)(sTl + e * 200 + q * 8) = *(const short8*)g;
    }
    for (int i = tid; i < 64 * 64; i += 256) {
        int e = i >> 6, c = i & 63;
        float v = (c < NBRD) ? ea[(long)(e0 + e) * NBRD + c] : 0.f;
        sTl[e * 200 + 128 + c] = f2b(v);
    }
    __syncthreads();

    const int lane = tid & 63, w = tid >> 6;
    const int n16 = lane & 15, quad = lane >> 4;

    short8 A0[6], A1[6];
    {
        const u16* b0 = wT + (16 * w + n16) * 192 + quad * 8;
        const u16* b1 = wT + (16 * (w + 4) + n16) * 192 + quad * 8;
#pragma unroll
        for (int ks = 0; ks < 6; ks++) {
            A0[ks] = *(const short8*)(b0 + ks * 32);
            A1[ks] = *(const short8*)(b1 + ks * 32);
        }
    }

    const int j0 = 16 * w + 4 * quad;
    float s0[4] = {0,0,0,0}, q0[4] = {0,0,0,0}, s1[4] = {0,0,0,0}, q1[4] = {0,0,0,0};

    for (int t = 0; t < 4; t++) {
        const u16* row = sTl + (16 * t + n16) * 200 + quad * 8;
        f32x4 acc0 = {0.f, 0.f, 0.f, 0.f}, acc1 = {0.f, 0.f, 0.f, 0.f};
#pragma unroll
        for (int ks = 0; ks < 6; ks++) {
            short8 b = *(const short8*)(row + ks * 32);
            acc0 = __builtin_amdgcn_mfma_f32_16x16x32_bf16(A0[ks], b, acc0, 0, 0, 0);
            acc1 = __builtin_amdgcn_mfma_f32_16x16x32_bf16(A1[ks], b, acc1, 0, 0, 0);
        }
#pragma unroll
        for (int r = 0; r < 4; r++) {
            s0[r] += acc0[r]; q0[r] = fmaf(acc0[r], acc0[r], q0[r]);
            s1[r] += acc1[r]; q1[r] = fmaf(acc1[r], acc1[r], q1[r]);
        }
        // write h row fragment: edge e0+16t+n16, cols j0..j0+3 and 64+j0..+3
        int ge = e0 + 16 * t + n16;
        u16* hp = h + (long)ge * 128 + j0;
        ushort4 v0 = make_ushort4(f2b(acc0[0]), f2b(acc0[1]), f2b(acc0[2]), f2b(acc0[3]));
        ushort4 v1 = make_ushort4(f2b(acc1[0]), f2b(acc1[1]), f2b(acc1[2]), f2b(acc1[3]));
        *(ushort4*)hp = v0;
        *(ushort4*)(hp + 64) = v1;
    }

    // stats: reduce over the 16 edge-lanes, one lane writes spread atomics
#pragma unroll
    for (int m = 1; m < 16; m <<= 1) {
#pragma unroll
        for (int r = 0; r < 4; r++) {
            s0[r] += __shfl_xor(s0[r], m); q0[r] += __shfl_xor(q0[r], m);
            s1[r] += __shfl_xor(s1[r], m); q1[r] += __shfl_xor(q1[r], m);
        }
    }
    if (n16 == 0) {
        float* sp = spread + (blockIdx.x & (NSPREAD - 1)) * 256;
#pragma unroll
        for (int r = 0; r < 4; r++) {
            atomicAdd(sp + j0 + r,       s0[r]);
            atomicAdd(sp + 128 + j0 + r, q0[r]);
            atomicAdd(sp + 64 + j0 + r,  s1[r]);
            atomicAdd(sp + 192 + j0 + r, q1[r]);
        }
    }
}

// ---------------- fallback two-pass GEMM (R2), used when ws too small ----------
template <int MODE>
__global__ __launch_bounds__(256) void k_gemm(
    const u16* __restrict__ afb, const float* __restrict__ ea,
    const int* __restrict__ ei, const u16* __restrict__ wT,
    const float* __restrict__ sc, float* __restrict__ outbuf)
{
    __shared__ __align__(16) u16 sTl[64 * 200];
    __shared__ int sSrc[64], sDst[64];
    const int tid = threadIdx.x;
    const int e0 = blockIdx.x * 64;

    if (tid < 64) sSrc[tid] = ei[e0 + tid];
    else if (tid < 128) sDst[tid - 64] = ei[NE + e0 + tid - 64];
    __syncthreads();
    for (int i = tid; i < 1024; i += 256) {
        int e = i >> 4, q = i & 15;
        const u16* g = (q < 8) ? (afb + (long)sSrc[e] * 64 + q * 8)
                               : (afb + (long)sDst[e] * 64 + (q - 8) * 8);
        *(short8*)(sTl + e * 200 + q * 8) = *(const short8*)g;
    }
    for (int i = tid; i < 64 * 64; i += 256) {
        int e = i >> 6, c = i & 63;
        float v = (c < NBRD) ? ea[(long)(e0 + e) * NBRD + c] : 0.f;
        sTl[e * 200 + 128 + c] = f2b(v);
    }
    __syncthreads();

    const int lane = tid & 63, w = tid >> 6;
    const int n16 = lane & 15, quad = lane >> 4;
    short8 A0[6], A1[6];
    {
        const u16* b0 = wT + (16 * w + n16) * 192 + quad * 8;
        const u16* b1 = wT + (16 * (w + 4) + n16) * 192 + quad * 8;
#pragma unroll
        for (int ks = 0; ks < 6; ks++) {
            A0[ks] = *(const short8*)(b0 + ks * 32);
            A1[ks] = *(const short8*)(b1 + ks * 32);
        }
    }
    const int j0 = 16 * w + 4 * quad;
    float s0[4] = {0,0,0,0}, q0[4] = {0,0,0,0}, s1[4] = {0,0,0,0}, q1[4] = {0,0,0,0};
    float scf[4], shf[4], scc[4], shc[4];
    if (MODE == 1) {
#pragma unroll
        for (int r = 0; r < 4; r++) {
            scf[r] = sc[j0 + r];        shf[r] = sc[128 + j0 + r];
            scc[r] = sc[64 + j0 + r];   shc[r] = sc[192 + j0 + r];
        }
    }
    for (int t = 0; t < 4; t++) {
        const u16* row = sTl + (16 * t + n16) * 200 + quad * 8;
        f32x4 acc0 = {0.f, 0.f, 0.f, 0.f}, acc1 = {0.f, 0.f, 0.f, 0.f};
#pragma unroll
        for (int ks = 0; ks < 6; ks++) {
            short8 b = *(const short8*)(row + ks * 32);
            acc0 = __builtin_amdgcn_mfma_f32_16x16x32_bf16(A0[ks], b, acc0, 0, 0, 0);
            acc1 = __builtin_amdgcn_mfma_f32_16x16x32_bf16(A1[ks], b, acc1, 0, 0, 0);
        }
        if (MODE == 0) {
#pragma unroll
            for (int r = 0; r < 4; r++) {
                s0[r] += acc0[r]; q0[r] = fmaf(acc0[r], acc0[r], q0[r]);
                s1[r] += acc1[r]; q1[r] = fmaf(acc1[r], acc1[r], q1[r]);
            }
        } else {
            int src = sSrc[16 * t + n16];
            float* dst = outbuf + (long)src * 64 + j0;
#pragma unroll
            for (int r = 0; r < 4; r++) {
                float f  = fmaf(acc0[r], scf[r], shf[r]);
                float cc = fmaf(acc1[r], scc[r], shc[r]);
                float sig = 1.f / (1.f + expf(-f));
                float sp  = fmaxf(cc, 0.f) + log1pf(expf(-fabsf(cc)));
                atomicAdd(dst + r, sig * sp);
            }
        }
    }
    if (MODE == 0) {
#pragma unroll
        for (int m = 1; m < 16; m <<= 1) {
#pragma unroll
            for (int r = 0; r < 4; r++) {
                s0[r] += __shfl_xor(s0[r], m); q0[r] += __shfl_xor(q0[r], m);
                s1[r] += __shfl_xor(s1[r], m); q1[r] += __shfl_xor(q1[r], m);
            }
        }
        if (n16 == 0) {
            float* sp = outbuf + (blockIdx.x & (NSPREAD - 1)) * 256;
#pragma unroll
            for (int r = 0; r < 4; r++) {
                atomicAdd(sp + j0 + r,       s0[r]);
                atomicAdd(sp + 128 + j0 + r, q0[r]);
                atomicAdd(sp + 64 + j0 + r,  s1[r]);
                atomicAdd(sp + 192 + j0 + r, q1[r]);
            }
        }
    }
}

// ---------------- bn1 finalize (fc_b folds out) ----------------
__global__ void k_bn1fin(const float* __restrict__ spread,
                         const float* __restrict__ g, const float* __restrict__ b,
                         float* __restrict__ sc)
{
    int c = threadIdx.x;  // 128
    float s = 0.f, q = 0.f;
    for (int k = 0; k < NSPREAD; k++) { s += spread[k * 256 + c]; q += spread[k * 256 + 128 + c]; }
    float mean_acc = s / (float)NE;
    float var = q / (float)NE - mean_acc * mean_acc;
    float scale = g[c] * rsqrtf(var + 1e-5f);
    sc[c] = scale;
    sc[128 + c] = b[c] - mean_acc * scale;
}

// ---------------- CSR gather: BN1 + gate + per-node sum (no atomics) ----------------
__global__ __launch_bounds__(256) void k_scatter(
    const u16* __restrict__ h, const int* __restrict__ ptr,
    const int* __restrict__ cnt, const int* __restrict__ eidx,
    const float* __restrict__ sc, float* __restrict__ summed)
{
    int tid = threadIdx.x;
    int n = blockIdx.x * 4 + (tid >> 6);   // one wave per node
    int l = tid & 63;
    float scf = sc[l],      shf = sc[128 + l];
    float scc = sc[64 + l], shc = sc[192 + l];
    int p0 = ptr[n], p1 = p0 + cnt[n];
    float acc = 0.f;
    int e_next = (p0 < p1) ? eidx[p0] : 0;
    for (int i = p0; i < p1; ) {
        int e = e_next;
        ++i;
        if (i < p1) e_next = eidx[i];
        const u16* hr = h + (long)e * 128;
        float f  = fmaf(b2f(hr[l]),      scf, shf);
        float cc = fmaf(b2f(hr[64 + l]), scc, shc);
        float sig = 1.f / (1.f + expf(-f));
        float sp  = fmaxf(cc, 0.f) + log1pf(expf(-fabsf(cc)));
        acc = fmaf(sig, sp, acc);
    }
    summed[(long)n * 64 + l] = acc;
}

// ---------------- bn2 stats ----------------
__global__ __launch_bounds__(256) void k_bn2stats(const float* __restrict__ summed,
                                                  float* __restrict__ acc2)
{
    int tid = threadIdx.x; int c = tid & 63; int sub = tid >> 6;
    float s = 0.f, q = 0.f;
    for (int r = blockIdx.x * 4 + sub; r < NN; r += 4 * 128) {
        float v = summed[(long)r * 64 + c]; s += v; q = fmaf(v, v, q);
    }
    __shared__ float rs[256], rq[256];
    rs[tid] = s; rq[tid] = q; __syncthreads();
    if (tid < 64) {
        s = rs[tid] + rs[tid + 64] + rs[tid + 128] + rs[tid + 192];
        q = rq[tid] + rq[tid + 64] + rq[tid + 128] + rq[tid + 192];
        atomicAdd(&acc2[tid], s);
        atomicAdd(&acc2[64 + tid], q);
    }
}

__global__ void k_bn2fin(const float* __restrict__ acc2,
                         const float* __restrict__ g, const float* __restrict__ b,
                         float* __restrict__ sc2)
{
    int c = threadIdx.x;  // 64
    float mean = acc2[c] / (float)NN;
    float var = acc2[64 + c] / (float)NN - mean * mean;
    float scale = g[c] * rsqrtf(var + 1e-5f);
    sc2[c] = scale;
    sc2[64 + c] = b[c] - mean * scale;
}

// ---------------- atom_out + silu + logits + segment max ----------------
__global__ __launch_bounds__(256) void k_nodepost(
    const float* __restrict__ summed, const float* __restrict__ sc2,
    const float* __restrict__ attW, const float* __restrict__ attb,
    const int* __restrict__ batch, float* __restrict__ out,
    float* __restrict__ elog, unsigned* __restrict__ segmax)
{
    int tid = threadIdx.x; int n = blockIdx.x * 4 + (tid >> 6); int c = tid & 63;
    float v = summed[(long)n * 64 + c];
    float ao = fmaf(v, sc2[c], sc2[64 + c]);
    out[(long)n * 64 + c] = ao;
    float h = ao / (1.f + expf(-ao));
    float p = h * attW[c];
#pragma unroll
    for (int off = 32; off; off >>= 1) p += __shfl_down(p, off, 64);
    if (c == 0) {
        float logit = p + attb[0];
        elog[n] = logit;
        unsigned u = __float_as_uint(logit);
        u = (u & 0x80000000u) ? ~u : (u | 0x80000000u);
        atomicMax(&segmax[batch[n]], u);
    }
}

__global__ void k_denom(const int* __restrict__ batch,
                        const unsigned* __restrict__ segmax,
                        float* __restrict__ elog, float* __restrict__ denom)
{
    int n = blockIdx.x * 256 + threadIdx.x;
    if (n >= NN) return;
    int b = batch[n];
    unsigned u = segmax[b];
    u = (u & 0x80000000u) ? (u & 0x7FFFFFFFu) : ~u;
    float e = expf(elog[n] - __uint_as_float(u));
    elog[n] = e;
    atomicAdd(&denom[b], e);
}

__global__ __launch_bounds__(256) void k_crys(
    const float* __restrict__ out, const float* __restrict__ elog,
    const float* __restrict__ denom, const int* __restrict__ batch,
    float* __restrict__ crys)
{
    int tid = threadIdx.x; int n = blockIdx.x * 4 + (tid >> 6); int c = tid & 63;
    int b = batch[n];
    float alpha = elog[n] / denom[b];
    float ao = out[(long)n * 64 + c];
    float h = ao / (1.f + expf(-ao));
    atomicAdd(&crys[b * 64 + c], alpha * h);
}

__global__ void k_final(const float* __restrict__ crys,
                        const float* __restrict__ outW, const float* __restrict__ outb,
                        float* __restrict__ out)
{
    int g = blockIdx.x; int c = threadIdx.x;
    float p = crys[g * 64 + c] * outW[c];
#pragma unroll
    for (int off = 32; off; off >>= 1) p += __shfl_down(p, off, 64);
    if (c == 0) out[(long)NN * 64 + g] = p + outb[0];
}

extern "C" void kernel_launch(void* const* d_in, const int* in_sizes, int n_in,
                              void* d_out, int out_size, void* d_ws, size_t ws_size,
                              hipStream_t stream)
{
    const float* x    = (const float*)d_in[0];
    const float* eatt = (const float*)d_in[1];
    const float* lf   = (const float*)d_in[2];
    const int*   ei   = (const int*)d_in[3];
    const int*   batch= (const int*)d_in[4];
    const float* embW = (const float*)d_in[5];
    const float* embB = (const float*)d_in[6];
    const float* fcW  = (const float*)d_in[7];
    // d_in[8] fc_b folds into bn1 shift
    const float* bn1g = (const float*)d_in[9];
    const float* bn1b = (const float*)d_in[10];
    const float* bn2g = (const float*)d_in[11];
    const float* bn2b = (const float*)d_in[12];
    const float* attW = (const float*)d_in[13];
    const float* attB = (const float*)d_in[14];
    const float* outW = (const float*)d_in[15];
    const float* outB = (const float*)d_in[16];
    float* out = (float*)d_out;
    float* ws  = (float*)d_ws;

    u16* afb = (u16*)(ws + OFF_AFB);
    u16* wT  = (u16*)(ws + OFF_WT);
    int* cnt  = (int*)(ws + OFF_CNT);
    int* ptr  = (int*)(ws + OFF_PTR);
    int* head = (int*)(ws + OFF_HEAD);
    int* bsum = (int*)(ws + OFF_BSUM);
    int* bofs = (int*)(ws + OFF_BOFS);
    int* eidx = (int*)(ws + OFF_EIDX);
    u16* h    = (u16*)(ws + OFF_H);

    const bool big = ws_size >= (size_t)OFF_BIG_END * sizeof(float);

    k_embed<<<12500, 256, 0, stream>>>(x, lf, embW, embB, afb);
    k_prepw<<<96, 256, 0, stream>>>(fcW, wT);

    if (big) {
        // zero: bn1 spread, bn2acc, segmax, denom, crys, cnt  (OFF_BN1SPR..OFF_PTR)
        hipMemsetAsync(ws + OFF_BN1SPR, 0,
                       (size_t)(OFF_PTR - OFF_BN1SPR) * sizeof(float), stream);
        // CSR over src
        k_hist<<<(NE + 255) / 256, 256, 0, stream>>>(ei, cnt);
        k_partial<<<(NN + SCAN_B - 1) / SCAN_B, SCAN_B, 0, stream>>>(cnt, ptr, bsum);
        k_scanb<<<1, 256, 0, stream>>>(bsum, bofs, (NN + SCAN_B - 1) / SCAN_B);
        k_addofs<<<(NN + 255) / 256, 256, 0, stream>>>(ptr, bofs, head);
        k_fill<<<(NE + 255) / 256, 256, 0, stream>>>(ei, head, eidx);
        // single GEMM pass: h + stats, then BN coefs, then gather-scatter
        k_gemm_h<<<NE / 64, 256, 0, stream>>>(afb, eatt, ei, wT, h, ws + OFF_BN1SPR);
        k_bn1fin<<<1, 128, 0, stream>>>(ws + OFF_BN1SPR, bn1g, bn1b, ws + OFF_BN1SC);
        k_scatter<<<NN / 4, 256, 0, stream>>>(h, ptr, cnt, eidx, ws + OFF_BN1SC,
                                              ws + OFF_SUMMED);
    } else {
        // fallback: R2 two-pass with atomic scatter
        hipMemsetAsync(ws + OFF_SUMMED, 0,
                       (size_t)(OFF_CNT - OFF_SUMMED) * sizeof(float), stream);
        k_gemm<0><<<NE / 64, 256, 0, stream>>>(afb, eatt, ei, wT, ws + OFF_BN1SC,
                                               ws + OFF_BN1SPR);
        k_bn1fin<<<1, 128, 0, stream>>>(ws + OFF_BN1SPR, bn1g, bn1b, ws + OFF_BN1SC);
        k_gemm<1><<<NE / 64, 256, 0, stream>>>(afb, eatt, ei, wT, ws + OFF_BN1SC,
                                               ws + OFF_SUMMED);
    }

    k_bn2stats<<<128, 256, 0, stream>>>(ws + OFF_SUMMED, ws + OFF_BN2ACC);
    k_bn2fin<<<1, 64, 0, stream>>>(ws + OFF_BN2ACC, bn2g, bn2b, ws + OFF_BN2SC);
    k_nodepost<<<12500, 256, 0, stream>>>(ws + OFF_SUMMED, ws + OFF_BN2SC, attW, attB, batch,
                                          out, ws + OFF_ELOG, (unsigned*)(ws + OFF_SEGMAX));
    k_denom<<<196, 256, 0, stream>>>(batch, (const unsigned*)(ws + OFF_SEGMAX),
                                     ws + OFF_ELOG, ws + OFF_DENOM);
    k_crys<<<12500, 256, 0, stream>>>(out, ws + OFF_ELOG, ws + OFF_DENOM, batch,
                                      ws + OFF_CRYS);
    k_final<<<NG, 64, 0, stream>>>(ws + OFF_CRYS, outW, outB, out);
}